// Round 22
// baseline (76.981 us; speedup 1.0000x reference)
//
#include <hip/hip_runtime.h>
#include <math.h>

constexpr int cB  = 16;
constexpr int cN  = 64;
constexpr int EMB = 32;
constexpr int NL  = 3;
constexpr int CDIM = 24;
constexpr int LOD = NL * CDIM;      // 72
constexpr int NB  = 10;
constexpr int H   = 150;
constexpr int CR  = 219;
constexpr int C2  = 438;
constexpr int HD  = 128;
constexpr int NSP = 6;              // species count
constexpr int GC  = NSP * LOD;      // 432 G-columns
constexpr int GCP = 512;            // padded W2 row
constexpr int TBL = 512;            // r-table resolution (measured absmax 0.0)
constexpr float RADIUS = 2.0f;

__device__ __forceinline__ float sp5(float x) {
    return fmaxf(x, 0.0f) + 0.2f * log1pf(expf(-5.0f * fabsf(x)));
}
__device__ __forceinline__ float sp1(float x) {
    return fmaxf(x, 0.0f) + log1pf(expf(-fabsf(x)));
}

// Merged prologue kernel.
// blocks 0..89: W2[k][z*72+lo] = sum_i rW3[k][lo*32+i]*emb[z][i] (z-interleaved, 512-padded) + Pbz
// blocks 90..345: pad rW0/rW1/rW2 -> [.][152]; transpose c_W -> c_Wt[128][440]; zero pooled2
__global__ void __launch_bounds__(256) k_prep(const float* __restrict__ emb_W,
                                              const float* __restrict__ rW3,
                                              const float* __restrict__ rb3,
                                              const float* __restrict__ rW0,
                                              const float* __restrict__ rW1,
                                              const float* __restrict__ rW2,
                                              const float* __restrict__ c_W,
                                              float* __restrict__ W2,
                                              float* __restrict__ Pbz,
                                              float* __restrict__ rW0p,
                                              float* __restrict__ rW1p,
                                              float* __restrict__ rW2p,
                                              float* __restrict__ c_Wt,
                                              float* __restrict__ pooled2) {
    int bx = blockIdx.x;
    int t = threadIdx.x;
    __shared__ float e[EMB];
    if (bx < 90) {
        int z = bx / 15, hb = bx - (bx / 15) * 15;   // 6 x 15, 10 k-rows each
        if (t < EMB) e[t] = emb_W[z * EMB + t];
        __syncthreads();
        for (int o = t; o < 10 * LOD; o += 256) {
            int k = hb * 10 + o / LOD, lo = o % LOD;
            const float* wr = &rW3[(size_t)k * (LOD * EMB) + lo * EMB];
            float s = 0.0f;
            #pragma unroll
            for (int i = 0; i < EMB; ++i) s = fmaf(wr[i], e[i], s);
            W2[(size_t)k * GCP + z * LOD + lo] = s;
        }
        if (z == 0) {  // zero the pad cols 432..511
            for (int o = t; o < 10 * (GCP - GC); o += 256) {
                int k = hb * 10 + o / (GCP - GC), c = GC + o % (GCP - GC);
                W2[(size_t)k * GCP + c] = 0.0f;
            }
        }
        if (hb == 0 && t < LOD) {
            float s = 0.0f;
            #pragma unroll
            for (int i = 0; i < EMB; ++i) s = fmaf(rb3[t * EMB + i], e[i], s);
            Pbz[z * LOD + t] = s;
        }
    } else {
        int pb = bx - 90;                            // 256 pad blocks
        int total = NB * 152 + 2 * H * 152 + HD * 440;   // 103440
        int total2 = total + cB * C2;                    // + pooled2 zeroing
        for (int i = pb * 256 + t; i < total2; i += 256 * 256) {
            if (i < NB * 152) {
                int r = i / 152, c = i - r * 152;
                rW0p[i] = (c < H) ? rW0[r * H + c] : 0.0f;
            } else if (i < NB * 152 + H * 152) {
                int j = i - NB * 152; int r = j / 152, c = j - r * 152;
                rW1p[j] = (c < H) ? rW1[r * H + c] : 0.0f;
            } else if (i < NB * 152 + 2 * H * 152) {
                int j = i - NB * 152 - H * 152; int r = j / 152, c = j - r * 152;
                rW2p[j] = (c < H) ? rW2[r * H + c] : 0.0f;
            } else if (i < total) {
                int j = i - NB * 152 - 2 * H * 152;
                int jj = j / 440, ch = j - jj * 440;
                c_Wt[j] = (ch < C2) ? c_W[ch * HD + jj] : 0.0f;
            } else {
                pooled2[i - total] = 0.0f;
            }
        }
    }
}

// Fused table chain, no weight staging (weights stream L1/L2, coalesced).
// 2 rows/block x 256 thr; thread map: a2 = t>>7 (row), jt = t&127 (col).
__global__ void __launch_bounds__(256) k_chain(const float* __restrict__ rW0p,
                                               const float* __restrict__ rb0,
                                               const float* __restrict__ rW1p,
                                               const float* __restrict__ rb1,
                                               const float* __restrict__ rW2p,
                                               const float* __restrict__ rb2,
                                               const float* __restrict__ W2,
                                               const float* __restrict__ Pbz,
                                               float* __restrict__ G) {
    const int row0 = blockIdx.x * 2;
    const int t = threadIdx.x;
    const int a2 = t >> 7;                   // 0..1 local row
    const int jt = t & 127;                  // col
    const bool hasx = (jt < 22);
    const int jx = hasx ? 128 + jt : 128;    // extra col (idle lanes read col 128, discard)

    __shared__ __align__(16) float bas[2][10];
    __shared__ __align__(16) float hA[2 * 152];
    __shared__ __align__(16) float hB[2 * 152];

    if (t < 2) {
        float r = (float)(row0 + t) * (RADIUS / (float)(TBL - 1));
        #pragma unroll
        for (int k = 0; k < NB; ++k) {
            float d = r * 4.5f - (float)k;
            float v = 0.0f;
            if (fabsf(d) < 1.0f) { float cc = cosf(1.57079632679489662f * d); v = cc * cc; }
            bas[t][k] = v;
        }
    }
    __syncthreads();

    // ---- L0: K=10 ----
    {
        float a0 = 0, ax = 0;
        #pragma unroll
        for (int k = 0; k < NB; ++k) {
            float x = bas[a2][k];
            a0 = fmaf(x, rW0p[k * 152 + jt], a0);
            ax = fmaf(x, rW0p[k * 152 + jx], ax);
        }
        hA[a2 * 152 + jt] = sp5(a0 + rb0[jt]);
        if (hasx) hA[a2 * 152 + 128 + jt] = sp5(ax + rb0[128 + jt]);
    }
    __syncthreads();

    // ---- L1 (hA->hB), L2 (hB->hA): K=150, weights direct from L1/L2 ----
    for (int layer = 0; layer < 2; ++layer) {
        const float* W   = layer ? rW2p : rW1p;
        const float* bb  = layer ? rb2 : rb1;
        const float* src = layer ? hB : hA;
        float*       dst = layer ? hA : hB;
        float a0 = 0, ax = 0;
        const float* xs = &src[a2 * 152];
        #pragma unroll 10
        for (int k = 0; k < H; ++k) {
            float x = xs[k];
            const float* wr = &W[k * 152];
            a0 = fmaf(x, wr[jt], a0);
            ax = fmaf(x, wr[jx], ax);
        }
        dst[a2 * 152 + jt] = sp5(a0 + bb[jt]);
        if (hasx) dst[a2 * 152 + 128 + jt] = sp5(ax + bb[128 + jt]);
        __syncthreads();
    }

    // ---- G: out[row][c] = sum_k hA[row][k]*W2[k][c] + Pbz[c], c = 4jt..4jt+4 ----
    if (jt < 108) {
        const int g0 = 4 * jt;
        float4 c0 = {0, 0, 0, 0};
        const float* xs = &hA[a2 * 152];
        #pragma unroll 10
        for (int k = 0; k < H; ++k) {
            float x = xs[k];
            float4 w = *(const float4*)&W2[(size_t)k * GCP + g0];
            c0.x = fmaf(x, w.x, c0.x); c0.y = fmaf(x, w.y, c0.y);
            c0.z = fmaf(x, w.z, c0.z); c0.w = fmaf(x, w.w, c0.w);
        }
        int row = row0 + a2;
        float4 p = *(const float4*)&Pbz[g0];
        float4 o;
        o.x = c0.x + p.x; o.y = c0.y + p.y; o.z = c0.z + p.z; o.w = c0.w + p.w;
        *(float4*)&G[(size_t)row * GC + g0] = o;
    }
}

// per (b,a): mask + G-lerp -> ps; Y-reduce -> xr[219]; write feats0 row; xv^2 -> pooled2 half 1
__global__ void __launch_bounds__(256) k_redA(const float* __restrict__ xyz,
                                              const int* __restrict__ Z,
                                              const float* __restrict__ body23,
                                              const float* __restrict__ G,
                                              float* __restrict__ feats0,
                                              float* __restrict__ pooled2) {
    int ba = blockIdx.x;
    int b = ba >> 6, a = ba & 63;
    int t = threadIdx.x;
    __shared__ float ym[64][12];
    __shared__ float ps[64][76];
    __shared__ float xr[224];
    __shared__ int t0s[64];
    __shared__ float wls[64];
    __shared__ int zs[64];
    __shared__ int msks[64];
    if (t < 64) {
        int n = t;
        float ax = xyz[((size_t)b * cN + a) * 3 + 0];
        float ay = xyz[((size_t)b * cN + a) * 3 + 1];
        float az = xyz[((size_t)b * cN + a) * 3 + 2];
        float d0 = ax - xyz[((size_t)b * cN + n) * 3 + 0];
        float d1 = ay - xyz[((size_t)b * cN + n) * 3 + 1];
        float d2 = az - xyz[((size_t)b * cN + n) * 3 + 2];
        float s = d0 * d0 + d1 * d1 + d2 * d2;
        float r = sqrtf(s + 1e-12f);
        msks[n] = (r < RADIUS) && (r > 1e-6f);
        float u = r * ((float)(TBL - 1) / RADIUS);
        int t0 = (int)u;
        if (t0 > TBL - 2) t0 = TBL - 2;
        t0s[n] = t0;
        wls[n] = u - (float)t0;
        zs[n] = Z[b * cN + n];
        float inv = 1.0f / r;
        float x = d0 * inv, y = d1 * inv, z = d2 * inv;
        ym[n][0] = 0.28209479177387814f;
        ym[n][1] = 0.4886025119029199f * y;
        ym[n][2] = 0.4886025119029199f * z;
        ym[n][3] = 0.4886025119029199f * x;
        ym[n][4] = 1.0925484305920792f * x * y;
        ym[n][5] = 1.0925484305920792f * y * z;
        ym[n][6] = 0.31539156525252005f * (3.0f * z * z - 1.0f);
        ym[n][7] = 1.0925484305920792f * x * z;
        ym[n][8] = 0.5462742152960396f * (x * x - y * y);
    }
    __syncthreads();
    for (int i = t; i < 64 * LOD; i += 256) {
        int n = i / LOD, lo = i - n * LOD;
        float v = 0.0f;
        if (msks[n]) {
            const float* g = &G[(size_t)t0s[n] * GC + zs[n] * LOD + lo];
            float g0 = g[0], g1 = g[GC];
            v = g0 + wls[n] * (g1 - g0);
        }
        ps[n][lo] = v;
    }
    __syncthreads();
    if (t < 216) {
        int lo, yi;
        if (t < 24) { lo = t; yi = 0; }
        else if (t < 96) { int q = t - 24; int o = q / 3; lo = 24 + o; yi = 1 + (q - o * 3); }
        else { int q = t - 96; int o = q / 5; lo = 48 + o; yi = 4 + (q - o * 5); }
        float acc = 0.0f;
        #pragma unroll 4
        for (int n = 0; n < cN; ++n)
            acc = fmaf(ps[n][lo], ym[n][yi], acc);
        xr[3 + t] = acc * 0.125f;
    } else if (t < 219) {
        xr[t - 216] = body23[(size_t)ba * 3 + (t - 216)];
    }
    __syncthreads();
    if (t < CR) {
        float xv = xr[t];
        feats0[(size_t)ba * CR + t] = xv;
        atomicAdd(&pooled2[b * C2 + t], xv * xv);
    }
}

// residual GEMM: 4 same-b atoms/block; each res_W load feeds 4 FMA chains.
// o = xv + sp5(res_b + xr.res_W); accumulate o^2 into pooled2 half 2.
__global__ void __launch_bounds__(256) k_redB(const float* __restrict__ feats0,
                                              const float* __restrict__ res_W,
                                              const float* __restrict__ res_b,
                                              float* __restrict__ pooled2) {
    int bp = blockIdx.x;                     // 256 blocks: b = bp>>4, atoms 4*(bp&15)..+3
    int b = bp >> 4;
    int a0 = (bp & 15) * 4;
    int t = threadIdx.x;
    __shared__ float xs[4][224];
    for (int i = t; i < 4 * CR; i += 256) {
        int r = i / CR, c = i - r * CR;
        xs[r][c] = feats0[(size_t)(b * cN + a0 + r) * CR + c];
    }
    __syncthreads();
    if (t < CR) {
        float s0 = 0.0f, s1 = 0.0f, s2 = 0.0f, s3 = 0.0f;
        #pragma unroll 4
        for (int k = 0; k < CR; ++k) {
            float w = res_W[(size_t)k * CR + t];
            s0 = fmaf(xs[0][k], w, s0);
            s1 = fmaf(xs[1][k], w, s1);
            s2 = fmaf(xs[2][k], w, s2);
            s3 = fmaf(xs[3][k], w, s3);
        }
        float rb = res_b[t];
        float o0 = xs[0][t] + sp5(rb + s0);
        float o1 = xs[1][t] + sp5(rb + s1);
        float o2 = xs[2][t] + sp5(rb + s2);
        float o3 = xs[3][t] + sp5(rb + s3);
        atomicAdd(&pooled2[b * C2 + CR + t], (o0 * o0 + o1 * o1) + (o2 * o2 + o3 * o3));
    }
}

// hh[b][j] = sp1(sqrt(pooled2[b]) . c_Wt[j] + c_b[j]); one block per column j, 64 lanes
__global__ void __launch_bounds__(64) k_head1(const float* __restrict__ pooled2,
                                              const float* __restrict__ c_Wt,
                                              const float* __restrict__ c_b,
                                              float* __restrict__ hh) {
    int j = blockIdx.x;
    int l = threadIdx.x;
    float acc[cB];
    #pragma unroll
    for (int b = 0; b < cB; ++b) acc[b] = 0.0f;
    const float* wr = &c_Wt[j * 440];
    for (int ch = l; ch < C2; ch += 64) {
        float wv = wr[ch];
        #pragma unroll
        for (int b = 0; b < cB; ++b)
            acc[b] = fmaf(sqrtf(pooled2[b * C2 + ch]), wv, acc[b]);
    }
    #pragma unroll
    for (int off = 32; off >= 1; off >>= 1) {
        #pragma unroll
        for (int b = 0; b < cB; ++b) acc[b] += __shfl_xor(acc[b], off, 64);
    }
    if (l == 0) {
        float cb = c_b[j];
        #pragma unroll
        for (int b = 0; b < cB; ++b) hh[b * HD + j] = sp1(acc[b] + cb);
    }
}

// BN (training batch stats) + softplus + output linear + sigmoid; single small block
__global__ void __launch_bounds__(128) k_head2(const float* __restrict__ hh,
                                               const float* __restrict__ bn_g,
                                               const float* __restrict__ bn_b,
                                               const float* __restrict__ o_W,
                                               const float* __restrict__ o_b,
                                               float* __restrict__ out) {
    __shared__ float hh2[cB][HD];
    int t = threadIdx.x;                     // = column j
    float v[cB];
    float mu = 0.0f;
    #pragma unroll
    for (int b = 0; b < cB; ++b) { v[b] = hh[b * HD + t]; mu += v[b]; }
    mu *= (1.0f / cB);
    float var = 0.0f;
    #pragma unroll
    for (int b = 0; b < cB; ++b) { float d = v[b] - mu; var = fmaf(d, d, var); }
    var *= (1.0f / cB);
    float sc = bn_g[t] / sqrtf(var + 1e-5f);
    float bnb = bn_b[t];
    #pragma unroll
    for (int b = 0; b < cB; ++b) hh2[b][t] = sp1((v[b] - mu) * sc + bnb);
    __syncthreads();
    if (t < cB) {
        float s = o_b[0];
        for (int j = 0; j < HD; ++j) s = fmaf(hh2[t][j], o_W[j], s);
        out[t] = 1.0f / (1.0f + expf(-s));
    }
}

extern "C" void kernel_launch(void* const* d_in, const int* in_sizes, int n_in,
                              void* d_out, int out_size, void* d_ws, size_t ws_size,
                              hipStream_t stream) {
    const float* xyz    = (const float*)d_in[0];
    const int*   Z      = (const int*)d_in[1];
    const float* body23 = (const float*)d_in[2];
    const float* emb_W  = (const float*)d_in[3];
    const float* rW0    = (const float*)d_in[4];
    const float* rb0    = (const float*)d_in[5];
    const float* rW1    = (const float*)d_in[6];
    const float* rb1    = (const float*)d_in[7];
    const float* rW2    = (const float*)d_in[8];
    const float* rb2    = (const float*)d_in[9];
    const float* rW3    = (const float*)d_in[10];
    const float* rb3    = (const float*)d_in[11];
    const float* res_W  = (const float*)d_in[12];
    const float* res_b  = (const float*)d_in[13];
    const float* c_W    = (const float*)d_in[14];
    const float* c_b    = (const float*)d_in[15];
    const float* bn_g   = (const float*)d_in[16];
    const float* bn_b   = (const float*)d_in[17];
    const float* o_W    = (const float*)d_in[18];
    const float* o_b    = (const float*)d_in[19];

    float* w       = (float*)d_ws;
    float* W2      = w;                       // 150*512    = 76800
    float* Pbz     = W2 + 76800;              // 432
    float* rW0p    = Pbz + 432;               // 10*152     = 1520
    float* rW1p    = rW0p + 1520;             // 150*152    = 22800
    float* rW2p    = rW1p + 22800;            // 22800
    float* c_Wt    = rW2p + 22800;            // 128*440    = 56320
    float* G       = c_Wt + 56320;            // 512*432    = 221184
    float* feats0  = G + 221184;              // 1024*219   = 224256
    float* pooled2 = feats0 + 224256;         // 16*438     = 7008
    float* hh      = pooled2 + 7008;          // 16*128     = 2048
    (void)in_sizes; (void)n_in; (void)out_size; (void)ws_size;

    k_prep <<<346, 256, 0, stream>>>(emb_W, rW3, rb3, rW0, rW1, rW2, c_W,
                                     W2, Pbz, rW0p, rW1p, rW2p, c_Wt, pooled2);
    k_chain<<<TBL / 2, 256, 0, stream>>>(rW0p, rb0, rW1p, rb1, rW2p, rb2, W2, Pbz, G);
    k_redA <<<cB * cN, 256, 0, stream>>>(xyz, Z, body23, G, feats0, pooled2);
    k_redB <<<cB * cN / 4, 256, 0, stream>>>(feats0, res_W, res_b, pooled2);
    k_head1<<<HD, 64, 0, stream>>>(pooled2, c_Wt, c_b, hh);
    k_head2<<<1, 128, 0, stream>>>(hh, bn_g, bn_b, o_W, o_b, (float*)d_out);
}

// Round 23
// 76.100 us; speedup vs baseline: 1.0116x; 1.0116x over previous
//
#include <hip/hip_runtime.h>
#include <math.h>

constexpr int cB  = 16;
constexpr int cN  = 64;
constexpr int EMB = 32;
constexpr int NL  = 3;
constexpr int CDIM = 24;
constexpr int LOD = NL * CDIM;      // 72
constexpr int NB  = 10;
constexpr int H   = 150;
constexpr int CR  = 219;
constexpr int C2  = 438;
constexpr int HD  = 128;
constexpr int NSP = 6;              // species count
constexpr int GC  = NSP * LOD;      // 432 G-columns
constexpr int GCP = 512;            // padded W2 row
constexpr int TBL = 512;            // r-table resolution (measured absmax 0.0)
constexpr float RADIUS = 2.0f;

__device__ __forceinline__ float sp5(float x) {
    return fmaxf(x, 0.0f) + 0.2f * log1pf(expf(-5.0f * fabsf(x)));
}
__device__ __forceinline__ float sp1(float x) {
    return fmaxf(x, 0.0f) + log1pf(expf(-fabsf(x)));
}

// Merged prologue kernel.
// blocks 0..89: W2[k][z*72+lo] = sum_i rW3[k][lo*32+i]*emb[z][i] (z-interleaved, 512-padded) + Pbz
// blocks 90..345: pad rW0/rW1/rW2 -> [.][152]; transpose c_W -> c_Wt[128][440]; zero pooled2
__global__ void __launch_bounds__(256) k_prep(const float* __restrict__ emb_W,
                                              const float* __restrict__ rW3,
                                              const float* __restrict__ rb3,
                                              const float* __restrict__ rW0,
                                              const float* __restrict__ rW1,
                                              const float* __restrict__ rW2,
                                              const float* __restrict__ c_W,
                                              float* __restrict__ W2,
                                              float* __restrict__ Pbz,
                                              float* __restrict__ rW0p,
                                              float* __restrict__ rW1p,
                                              float* __restrict__ rW2p,
                                              float* __restrict__ c_Wt,
                                              float* __restrict__ pooled2) {
    int bx = blockIdx.x;
    int t = threadIdx.x;
    __shared__ float e[EMB];
    if (bx < 90) {
        int z = bx / 15, hb = bx - (bx / 15) * 15;   // 6 x 15, 10 k-rows each
        if (t < EMB) e[t] = emb_W[z * EMB + t];
        __syncthreads();
        for (int o = t; o < 10 * LOD; o += 256) {
            int k = hb * 10 + o / LOD, lo = o % LOD;
            const float* wr = &rW3[(size_t)k * (LOD * EMB) + lo * EMB];
            float s = 0.0f;
            #pragma unroll
            for (int i = 0; i < EMB; ++i) s = fmaf(wr[i], e[i], s);
            W2[(size_t)k * GCP + z * LOD + lo] = s;
        }
        if (z == 0) {  // zero the pad cols 432..511
            for (int o = t; o < 10 * (GCP - GC); o += 256) {
                int k = hb * 10 + o / (GCP - GC), c = GC + o % (GCP - GC);
                W2[(size_t)k * GCP + c] = 0.0f;
            }
        }
        if (hb == 0 && t < LOD) {
            float s = 0.0f;
            #pragma unroll
            for (int i = 0; i < EMB; ++i) s = fmaf(rb3[t * EMB + i], e[i], s);
            Pbz[z * LOD + t] = s;
        }
    } else {
        int pb = bx - 90;                            // 256 pad blocks
        int total = NB * 152 + 2 * H * 152 + HD * 440;   // 103440
        int total2 = total + cB * C2;                    // + pooled2 zeroing
        for (int i = pb * 256 + t; i < total2; i += 256 * 256) {
            if (i < NB * 152) {
                int r = i / 152, c = i - r * 152;
                rW0p[i] = (c < H) ? rW0[r * H + c] : 0.0f;
            } else if (i < NB * 152 + H * 152) {
                int j = i - NB * 152; int r = j / 152, c = j - r * 152;
                rW1p[j] = (c < H) ? rW1[r * H + c] : 0.0f;
            } else if (i < NB * 152 + 2 * H * 152) {
                int j = i - NB * 152 - H * 152; int r = j / 152, c = j - r * 152;
                rW2p[j] = (c < H) ? rW2[r * H + c] : 0.0f;
            } else if (i < total) {
                int j = i - NB * 152 - 2 * H * 152;
                int jj = j / 440, ch = j - jj * 440;
                c_Wt[j] = (ch < C2) ? c_W[ch * HD + jj] : 0.0f;
            } else {
                pooled2[i - total] = 0.0f;
            }
        }
    }
}

// Fused table chain, no weight staging (weights stream L1/L2, coalesced).
// 2 rows/block x 256 thr; thread map: a2 = t>>7 (row), jt = t&127 (col).
__global__ void __launch_bounds__(256) k_chain(const float* __restrict__ rW0p,
                                               const float* __restrict__ rb0,
                                               const float* __restrict__ rW1p,
                                               const float* __restrict__ rb1,
                                               const float* __restrict__ rW2p,
                                               const float* __restrict__ rb2,
                                               const float* __restrict__ W2,
                                               const float* __restrict__ Pbz,
                                               float* __restrict__ G) {
    const int row0 = blockIdx.x * 2;
    const int t = threadIdx.x;
    const int a2 = t >> 7;                   // 0..1 local row
    const int jt = t & 127;                  // col
    const bool hasx = (jt < 22);
    const int jx = hasx ? 128 + jt : 128;    // extra col (idle lanes read col 128, discard)

    __shared__ __align__(16) float bas[2][10];
    __shared__ __align__(16) float hA[2 * 152];
    __shared__ __align__(16) float hB[2 * 152];

    if (t < 2) {
        float r = (float)(row0 + t) * (RADIUS / (float)(TBL - 1));
        #pragma unroll
        for (int k = 0; k < NB; ++k) {
            float d = r * 4.5f - (float)k;
            float v = 0.0f;
            if (fabsf(d) < 1.0f) { float cc = cosf(1.57079632679489662f * d); v = cc * cc; }
            bas[t][k] = v;
        }
    }
    __syncthreads();

    // ---- L0: K=10 ----
    {
        float a0 = 0, ax = 0;
        #pragma unroll
        for (int k = 0; k < NB; ++k) {
            float x = bas[a2][k];
            a0 = fmaf(x, rW0p[k * 152 + jt], a0);
            ax = fmaf(x, rW0p[k * 152 + jx], ax);
        }
        hA[a2 * 152 + jt] = sp5(a0 + rb0[jt]);
        if (hasx) hA[a2 * 152 + 128 + jt] = sp5(ax + rb0[128 + jt]);
    }
    __syncthreads();

    // ---- L1 (hA->hB), L2 (hB->hA): K=150, weights direct from L1/L2 ----
    for (int layer = 0; layer < 2; ++layer) {
        const float* W   = layer ? rW2p : rW1p;
        const float* bb  = layer ? rb2 : rb1;
        const float* src = layer ? hB : hA;
        float*       dst = layer ? hA : hB;
        float a0 = 0, ax = 0;
        const float* xs = &src[a2 * 152];
        #pragma unroll 10
        for (int k = 0; k < H; ++k) {
            float x = xs[k];
            const float* wr = &W[k * 152];
            a0 = fmaf(x, wr[jt], a0);
            ax = fmaf(x, wr[jx], ax);
        }
        dst[a2 * 152 + jt] = sp5(a0 + bb[jt]);
        if (hasx) dst[a2 * 152 + 128 + jt] = sp5(ax + bb[128 + jt]);
        __syncthreads();
    }

    // ---- G: out[row][c] = sum_k hA[row][k]*W2[k][c] + Pbz[c], c = 4jt..4jt+4 ----
    if (jt < 108) {
        const int g0 = 4 * jt;
        float4 c0 = {0, 0, 0, 0};
        const float* xs = &hA[a2 * 152];
        #pragma unroll 10
        for (int k = 0; k < H; ++k) {
            float x = xs[k];
            float4 w = *(const float4*)&W2[(size_t)k * GCP + g0];
            c0.x = fmaf(x, w.x, c0.x); c0.y = fmaf(x, w.y, c0.y);
            c0.z = fmaf(x, w.z, c0.z); c0.w = fmaf(x, w.w, c0.w);
        }
        int row = row0 + a2;
        float4 p = *(const float4*)&Pbz[g0];
        float4 o;
        o.x = c0.x + p.x; o.y = c0.y + p.y; o.z = c0.z + p.z; o.w = c0.w + p.w;
        *(float4*)&G[(size_t)row * GC + g0] = o;
    }
}

// per (b,a): mask + COMPACTED float4 G-lerp -> ps[ci]; Y-reduce over cnt; write feats0;
// xv^2 -> pooled2 half 1.
__global__ void __launch_bounds__(256) k_redA(const float* __restrict__ xyz,
                                              const int* __restrict__ Z,
                                              const float* __restrict__ body23,
                                              const float* __restrict__ G,
                                              float* __restrict__ feats0,
                                              float* __restrict__ pooled2) {
    int ba = blockIdx.x;
    int b = ba >> 6, a = ba & 63;
    int t = threadIdx.x;
    __shared__ float ym[64][12];
    __shared__ float ymc[64][12];
    __shared__ __align__(16) float ps[64][76];
    __shared__ float xr[224];
    __shared__ int t0s[64];
    __shared__ float wls[64];
    __shared__ int zs[64];
    __shared__ int msks[64];
    __shared__ int alist[64];
    __shared__ int cnt_s;
    if (t < 64) {
        int n = t;
        float ax = xyz[((size_t)b * cN + a) * 3 + 0];
        float ay = xyz[((size_t)b * cN + a) * 3 + 1];
        float az = xyz[((size_t)b * cN + a) * 3 + 2];
        float d0 = ax - xyz[((size_t)b * cN + n) * 3 + 0];
        float d1 = ay - xyz[((size_t)b * cN + n) * 3 + 1];
        float d2 = az - xyz[((size_t)b * cN + n) * 3 + 2];
        float s = d0 * d0 + d1 * d1 + d2 * d2;
        float r = sqrtf(s + 1e-12f);
        msks[n] = (r < RADIUS) && (r > 1e-6f);
        float u = r * ((float)(TBL - 1) / RADIUS);
        int t0 = (int)u;
        if (t0 > TBL - 2) t0 = TBL - 2;
        t0s[n] = t0;
        wls[n] = u - (float)t0;
        zs[n] = Z[b * cN + n];
        float inv = 1.0f / r;
        float x = d0 * inv, y = d1 * inv, z = d2 * inv;
        ym[n][0] = 0.28209479177387814f;
        ym[n][1] = 0.4886025119029199f * y;
        ym[n][2] = 0.4886025119029199f * z;
        ym[n][3] = 0.4886025119029199f * x;
        ym[n][4] = 1.0925484305920792f * x * y;
        ym[n][5] = 1.0925484305920792f * y * z;
        ym[n][6] = 0.31539156525252005f * (3.0f * z * z - 1.0f);
        ym[n][7] = 1.0925484305920792f * x * z;
        ym[n][8] = 0.5462742152960396f * (x * x - y * y);
    }
    __syncthreads();
    if (t == 0) {
        int c = 0;
        for (int n = 0; n < 64; ++n) if (msks[n]) alist[c++] = n;
        cnt_s = c;
    }
    __syncthreads();
    int cnt = cnt_s;
    // compact ym rows
    for (int i = t; i < cnt * 9; i += 256) {
        int ci = i / 9, yi = i - ci * 9;
        ymc[ci][yi] = ym[alist[ci]][yi];
    }
    // compacted float4 gather+lerp: 18 float4 groups per active neighbor
    for (int i = t; i < cnt * 18; i += 256) {
        int ci = i / 18, q = i - ci * 18;
        int n = alist[ci];
        const float* g = &G[(size_t)t0s[n] * GC + zs[n] * LOD + 4 * q];
        float4 g0 = *(const float4*)g;
        float4 g1 = *(const float4*)(g + GC);
        float wl = wls[n];
        float4 v;
        v.x = g0.x + wl * (g1.x - g0.x);
        v.y = g0.y + wl * (g1.y - g0.y);
        v.z = g0.z + wl * (g1.z - g0.z);
        v.w = g0.w + wl * (g1.w - g0.w);
        *(float4*)&ps[ci][4 * q] = v;
    }
    __syncthreads();
    if (t < 216) {
        int lo, yi;
        if (t < 24) { lo = t; yi = 0; }
        else if (t < 96) { int q = t - 24; int o = q / 3; lo = 24 + o; yi = 1 + (q - o * 3); }
        else { int q = t - 96; int o = q / 5; lo = 48 + o; yi = 4 + (q - o * 5); }
        float acc = 0.0f;
        #pragma unroll 4
        for (int ci = 0; ci < cnt; ++ci)
            acc = fmaf(ps[ci][lo], ymc[ci][yi], acc);
        xr[3 + t] = acc * 0.125f;
    } else if (t < 219) {
        xr[t - 216] = body23[(size_t)ba * 3 + (t - 216)];
    }
    __syncthreads();
    if (t < CR) {
        float xv = xr[t];
        feats0[(size_t)ba * CR + t] = xv;
        atomicAdd(&pooled2[b * C2 + t], xv * xv);
    }
}

// residual GEMM: 4 same-b atoms/block; each res_W load feeds 4 FMA chains.
// o = xv + sp5(res_b + xr.res_W); accumulate o^2 into pooled2 half 2.
__global__ void __launch_bounds__(256) k_redB(const float* __restrict__ feats0,
                                              const float* __restrict__ res_W,
                                              const float* __restrict__ res_b,
                                              float* __restrict__ pooled2) {
    int bp = blockIdx.x;                     // 256 blocks: b = bp>>4, atoms 4*(bp&15)..+3
    int b = bp >> 4;
    int a0 = (bp & 15) * 4;
    int t = threadIdx.x;
    __shared__ float xs[4][224];
    for (int i = t; i < 4 * CR; i += 256) {
        int r = i / CR, c = i - r * CR;
        xs[r][c] = feats0[(size_t)(b * cN + a0 + r) * CR + c];
    }
    __syncthreads();
    if (t < CR) {
        float s0 = 0.0f, s1 = 0.0f, s2 = 0.0f, s3 = 0.0f;
        #pragma unroll 4
        for (int k = 0; k < CR; ++k) {
            float w = res_W[(size_t)k * CR + t];
            s0 = fmaf(xs[0][k], w, s0);
            s1 = fmaf(xs[1][k], w, s1);
            s2 = fmaf(xs[2][k], w, s2);
            s3 = fmaf(xs[3][k], w, s3);
        }
        float rb = res_b[t];
        float o0 = xs[0][t] + sp5(rb + s0);
        float o1 = xs[1][t] + sp5(rb + s1);
        float o2 = xs[2][t] + sp5(rb + s2);
        float o3 = xs[3][t] + sp5(rb + s3);
        atomicAdd(&pooled2[b * C2 + CR + t], (o0 * o0 + o1 * o1) + (o2 * o2 + o3 * o3));
    }
}

// hh[b][j] = sp1(sqrt(pooled2[b]) . c_Wt[j] + c_b[j]); one block per column j, 64 lanes
__global__ void __launch_bounds__(64) k_head1(const float* __restrict__ pooled2,
                                              const float* __restrict__ c_Wt,
                                              const float* __restrict__ c_b,
                                              float* __restrict__ hh) {
    int j = blockIdx.x;
    int l = threadIdx.x;
    float acc[cB];
    #pragma unroll
    for (int b = 0; b < cB; ++b) acc[b] = 0.0f;
    const float* wr = &c_Wt[j * 440];
    for (int ch = l; ch < C2; ch += 64) {
        float wv = wr[ch];
        #pragma unroll
        for (int b = 0; b < cB; ++b)
            acc[b] = fmaf(sqrtf(pooled2[b * C2 + ch]), wv, acc[b]);
    }
    #pragma unroll
    for (int off = 32; off >= 1; off >>= 1) {
        #pragma unroll
        for (int b = 0; b < cB; ++b) acc[b] += __shfl_xor(acc[b], off, 64);
    }
    if (l == 0) {
        float cb = c_b[j];
        #pragma unroll
        for (int b = 0; b < cB; ++b) hh[b * HD + j] = sp1(acc[b] + cb);
    }
}

// BN (training batch stats) + softplus + output linear + sigmoid; single small block
__global__ void __launch_bounds__(128) k_head2(const float* __restrict__ hh,
                                               const float* __restrict__ bn_g,
                                               const float* __restrict__ bn_b,
                                               const float* __restrict__ o_W,
                                               const float* __restrict__ o_b,
                                               float* __restrict__ out) {
    __shared__ float hh2[cB][HD];
    int t = threadIdx.x;                     // = column j
    float v[cB];
    float mu = 0.0f;
    #pragma unroll
    for (int b = 0; b < cB; ++b) { v[b] = hh[b * HD + t]; mu += v[b]; }
    mu *= (1.0f / cB);
    float var = 0.0f;
    #pragma unroll
    for (int b = 0; b < cB; ++b) { float d = v[b] - mu; var = fmaf(d, d, var); }
    var *= (1.0f / cB);
    float sc = bn_g[t] / sqrtf(var + 1e-5f);
    float bnb = bn_b[t];
    #pragma unroll
    for (int b = 0; b < cB; ++b) hh2[b][t] = sp1((v[b] - mu) * sc + bnb);
    __syncthreads();
    if (t < cB) {
        float s = o_b[0];
        for (int j = 0; j < HD; ++j) s = fmaf(hh2[t][j], o_W[j], s);
        out[t] = 1.0f / (1.0f + expf(-s));
    }
}

extern "C" void kernel_launch(void* const* d_in, const int* in_sizes, int n_in,
                              void* d_out, int out_size, void* d_ws, size_t ws_size,
                              hipStream_t stream) {
    const float* xyz    = (const float*)d_in[0];
    const int*   Z      = (const int*)d_in[1];
    const float* body23 = (const float*)d_in[2];
    const float* emb_W  = (const float*)d_in[3];
    const float* rW0    = (const float*)d_in[4];
    const float* rb0    = (const float*)d_in[5];
    const float* rW1    = (const float*)d_in[6];
    const float* rb1    = (const float*)d_in[7];
    const float* rW2    = (const float*)d_in[8];
    const float* rb2    = (const float*)d_in[9];
    const float* rW3    = (const float*)d_in[10];
    const float* rb3    = (const float*)d_in[11];
    const float* res_W  = (const float*)d_in[12];
    const float* res_b  = (const float*)d_in[13];
    const float* c_W    = (const float*)d_in[14];
    const float* c_b    = (const float*)d_in[15];
    const float* bn_g   = (const float*)d_in[16];
    const float* bn_b   = (const float*)d_in[17];
    const float* o_W    = (const float*)d_in[18];
    const float* o_b    = (const float*)d_in[19];

    float* w       = (float*)d_ws;
    float* W2      = w;                       // 150*512    = 76800
    float* Pbz     = W2 + 76800;              // 432
    float* rW0p    = Pbz + 432;               // 10*152     = 1520
    float* rW1p    = rW0p + 1520;             // 150*152    = 22800
    float* rW2p    = rW1p + 22800;            // 22800
    float* c_Wt    = rW2p + 22800;            // 128*440    = 56320
    float* G       = c_Wt + 56320;            // 512*432    = 221184
    float* feats0  = G + 221184;              // 1024*219   = 224256
    float* pooled2 = feats0 + 224256;         // 16*438     = 7008
    float* hh      = pooled2 + 7008;          // 16*128     = 2048
    (void)in_sizes; (void)n_in; (void)out_size; (void)ws_size;

    k_prep <<<346, 256, 0, stream>>>(emb_W, rW3, rb3, rW0, rW1, rW2, c_W,
                                     W2, Pbz, rW0p, rW1p, rW2p, c_Wt, pooled2);
    k_chain<<<TBL / 2, 256, 0, stream>>>(rW0p, rb0, rW1p, rb1, rW2p, rb2, W2, Pbz, G);
    k_redA <<<cB * cN, 256, 0, stream>>>(xyz, Z, body23, G, feats0, pooled2);
    k_redB <<<cB * cN / 4, 256, 0, stream>>>(feats0, res_W, res_b, pooled2);
    k_head1<<<HD, 64, 0, stream>>>(pooled2, c_Wt, c_b, hh);
    k_head2<<<1, 128, 0, stream>>>(hh, bn_g, bn_b, o_W, o_b, (float*)d_out);
}

// Round 24
// 67.665 us; speedup vs baseline: 1.1377x; 1.1247x over previous
//
#include <hip/hip_runtime.h>
#include <math.h>

constexpr int cB  = 16;
constexpr int cN  = 64;
constexpr int EMB = 32;
constexpr int NL  = 3;
constexpr int CDIM = 24;
constexpr int LOD = NL * CDIM;      // 72
constexpr int NB  = 10;
constexpr int H   = 150;
constexpr int CR  = 219;
constexpr int C2  = 438;
constexpr int HD  = 128;
constexpr int NSP = 6;              // species count
constexpr int GC  = NSP * LOD;      // 432 G-columns
constexpr int GCP = 512;            // padded W2 row
constexpr int TBL = 512;            // r-table resolution (measured absmax 0.0)
constexpr float RADIUS = 2.0f;

__device__ __forceinline__ float sp5(float x) {
    return fmaxf(x, 0.0f) + 0.2f * log1pf(expf(-5.0f * fabsf(x)));
}
__device__ __forceinline__ float sp1(float x) {
    return fmaxf(x, 0.0f) + log1pf(expf(-fabsf(x)));
}

// Merged prologue kernel.
// blocks 0..89: W2 build + Pbz; blocks 90..345: pad/transpose + zero pooled2;
// blocks 346..409: warm-touch res_W into L2/L3 (cold-replay latency hiding).
__global__ void __launch_bounds__(256) k_prep(const float* __restrict__ emb_W,
                                              const float* __restrict__ rW3,
                                              const float* __restrict__ rb3,
                                              const float* __restrict__ rW0,
                                              const float* __restrict__ rW1,
                                              const float* __restrict__ rW2,
                                              const float* __restrict__ c_W,
                                              const float* __restrict__ res_W,
                                              float* __restrict__ W2,
                                              float* __restrict__ Pbz,
                                              float* __restrict__ rW0p,
                                              float* __restrict__ rW1p,
                                              float* __restrict__ rW2p,
                                              float* __restrict__ c_Wt,
                                              float* __restrict__ pooled2,
                                              float* __restrict__ touch) {
    int bx = blockIdx.x;
    int t = threadIdx.x;
    __shared__ float e[EMB];
    if (bx < 90) {
        int z = bx / 15, hb = bx - (bx / 15) * 15;   // 6 x 15, 10 k-rows each
        if (t < EMB) e[t] = emb_W[z * EMB + t];
        __syncthreads();
        for (int o = t; o < 10 * LOD; o += 256) {
            int k = hb * 10 + o / LOD, lo = o % LOD;
            const float* wr = &rW3[(size_t)k * (LOD * EMB) + lo * EMB];
            float s = 0.0f;
            #pragma unroll
            for (int i = 0; i < EMB; ++i) s = fmaf(wr[i], e[i], s);
            W2[(size_t)k * GCP + z * LOD + lo] = s;
        }
        if (z == 0) {  // zero the pad cols 432..511
            for (int o = t; o < 10 * (GCP - GC); o += 256) {
                int k = hb * 10 + o / (GCP - GC), c = GC + o % (GCP - GC);
                W2[(size_t)k * GCP + c] = 0.0f;
            }
        }
        if (hb == 0 && t < LOD) {
            float s = 0.0f;
            #pragma unroll
            for (int i = 0; i < EMB; ++i) s = fmaf(rb3[t * EMB + i], e[i], s);
            Pbz[z * LOD + t] = s;
        }
    } else if (bx < 346) {
        int pb = bx - 90;                            // 256 pad blocks
        int total = NB * 152 + 2 * H * 152 + HD * 440;   // 103440
        int total2 = total + cB * C2;                    // + pooled2 zeroing
        for (int i = pb * 256 + t; i < total2; i += 256 * 256) {
            if (i < NB * 152) {
                int r = i / 152, c = i - r * 152;
                rW0p[i] = (c < H) ? rW0[r * H + c] : 0.0f;
            } else if (i < NB * 152 + H * 152) {
                int j = i - NB * 152; int r = j / 152, c = j - r * 152;
                rW1p[j] = (c < H) ? rW1[r * H + c] : 0.0f;
            } else if (i < NB * 152 + 2 * H * 152) {
                int j = i - NB * 152 - H * 152; int r = j / 152, c = j - r * 152;
                rW2p[j] = (c < H) ? rW2[r * H + c] : 0.0f;
            } else if (i < total) {
                int j = i - NB * 152 - 2 * H * 152;
                int jj = j / 440, ch = j - jj * 440;
                c_Wt[j] = (ch < C2) ? c_W[ch * HD + jj] : 0.0f;
            } else {
                pooled2[i - total] = 0.0f;
            }
        }
    } else {
        // warm-touch res_W: 64 blocks x 256 thr, float4-coalesced; live dummy write
        int wb = bx - 346;
        const int n4 = (CR * CR) / 4;                // 11990 float4s
        float s = 0.0f;
        for (int i = wb * 256 + t; i < n4; i += 64 * 256) {
            float4 v = *(const float4*)&res_W[4 * i];
            s += v.x + v.y + v.z + v.w;
        }
        touch[wb * 256 + t] = s;                     // deterministic, keeps loads live
    }
}

// Fused table chain, no weight staging (weights stream L1/L2, coalesced).
// 2 rows/block x 256 thr; thread map: a2 = t>>7 (row), jt = t&127 (col).
__global__ void __launch_bounds__(256) k_chain(const float* __restrict__ rW0p,
                                               const float* __restrict__ rb0,
                                               const float* __restrict__ rW1p,
                                               const float* __restrict__ rb1,
                                               const float* __restrict__ rW2p,
                                               const float* __restrict__ rb2,
                                               const float* __restrict__ W2,
                                               const float* __restrict__ Pbz,
                                               float* __restrict__ G) {
    const int row0 = blockIdx.x * 2;
    const int t = threadIdx.x;
    const int a2 = t >> 7;                   // 0..1 local row
    const int jt = t & 127;                  // col
    const bool hasx = (jt < 22);
    const int jx = hasx ? 128 + jt : 128;    // extra col (idle lanes read col 128, discard)

    __shared__ __align__(16) float bas[2][10];
    __shared__ __align__(16) float hA[2 * 152];
    __shared__ __align__(16) float hB[2 * 152];

    if (t < 2) {
        float r = (float)(row0 + t) * (RADIUS / (float)(TBL - 1));
        #pragma unroll
        for (int k = 0; k < NB; ++k) {
            float d = r * 4.5f - (float)k;
            float v = 0.0f;
            if (fabsf(d) < 1.0f) { float cc = cosf(1.57079632679489662f * d); v = cc * cc; }
            bas[t][k] = v;
        }
    }
    __syncthreads();

    // ---- L0: K=10 ----
    {
        float a0 = 0, ax = 0;
        #pragma unroll
        for (int k = 0; k < NB; ++k) {
            float x = bas[a2][k];
            a0 = fmaf(x, rW0p[k * 152 + jt], a0);
            ax = fmaf(x, rW0p[k * 152 + jx], ax);
        }
        hA[a2 * 152 + jt] = sp5(a0 + rb0[jt]);
        if (hasx) hA[a2 * 152 + 128 + jt] = sp5(ax + rb0[128 + jt]);
    }
    __syncthreads();

    // ---- L1 (hA->hB), L2 (hB->hA): K=150, weights direct from L1/L2 ----
    for (int layer = 0; layer < 2; ++layer) {
        const float* W   = layer ? rW2p : rW1p;
        const float* bb  = layer ? rb2 : rb1;
        const float* src = layer ? hB : hA;
        float*       dst = layer ? hA : hB;
        float a0 = 0, ax = 0;
        const float* xs = &src[a2 * 152];
        #pragma unroll 10
        for (int k = 0; k < H; ++k) {
            float x = xs[k];
            const float* wr = &W[k * 152];
            a0 = fmaf(x, wr[jt], a0);
            ax = fmaf(x, wr[jx], ax);
        }
        dst[a2 * 152 + jt] = sp5(a0 + bb[jt]);
        if (hasx) dst[a2 * 152 + 128 + jt] = sp5(ax + bb[128 + jt]);
        __syncthreads();
    }

    // ---- G: out[row][c] = sum_k hA[row][k]*W2[k][c] + Pbz[c], c = 4jt..4jt+4 ----
    if (jt < 108) {
        const int g0 = 4 * jt;
        float4 c0 = {0, 0, 0, 0};
        const float* xs = &hA[a2 * 152];
        #pragma unroll 10
        for (int k = 0; k < H; ++k) {
            float x = xs[k];
            float4 w = *(const float4*)&W2[(size_t)k * GCP + g0];
            c0.x = fmaf(x, w.x, c0.x); c0.y = fmaf(x, w.y, c0.y);
            c0.z = fmaf(x, w.z, c0.z); c0.w = fmaf(x, w.w, c0.w);
        }
        int row = row0 + a2;
        float4 p = *(const float4*)&Pbz[g0];
        float4 o;
        o.x = c0.x + p.x; o.y = c0.y + p.y; o.z = c0.z + p.z; o.w = c0.w + p.w;
        *(float4*)&G[(size_t)row * GC + g0] = o;
    }
}

// per (b,a): ballot-compacted mask + float4 G-lerp -> ps[ci]; Y-reduce over cnt;
// write feats0; xv^2 -> pooled2 half 1.
__global__ void __launch_bounds__(256) k_redA(const float* __restrict__ xyz,
                                              const int* __restrict__ Z,
                                              const float* __restrict__ body23,
                                              const float* __restrict__ G,
                                              float* __restrict__ feats0,
                                              float* __restrict__ pooled2) {
    int ba = blockIdx.x;
    int b = ba >> 6, a = ba & 63;
    int t = threadIdx.x;
    __shared__ float ym[64][12];
    __shared__ float ymc[64][12];
    __shared__ __align__(16) float ps[64][76];
    __shared__ float xr[224];
    __shared__ int t0s[64];
    __shared__ float wls[64];
    __shared__ int zs[64];
    __shared__ int alist[64];
    __shared__ int cnt_s;
    if (t < 64) {
        int n = t;
        float ax = xyz[((size_t)b * cN + a) * 3 + 0];
        float ay = xyz[((size_t)b * cN + a) * 3 + 1];
        float az = xyz[((size_t)b * cN + a) * 3 + 2];
        float d0 = ax - xyz[((size_t)b * cN + n) * 3 + 0];
        float d1 = ay - xyz[((size_t)b * cN + n) * 3 + 1];
        float d2 = az - xyz[((size_t)b * cN + n) * 3 + 2];
        float s = d0 * d0 + d1 * d1 + d2 * d2;
        float r = sqrtf(s + 1e-12f);
        bool m = (r < RADIUS) && (r > 1e-6f);
        float u = r * ((float)(TBL - 1) / RADIUS);
        int t0 = (int)u;
        if (t0 > TBL - 2) t0 = TBL - 2;
        t0s[n] = t0;
        wls[n] = u - (float)t0;
        zs[n] = Z[b * cN + n];
        float inv = 1.0f / r;
        float x = d0 * inv, y = d1 * inv, z = d2 * inv;
        ym[n][0] = 0.28209479177387814f;
        ym[n][1] = 0.4886025119029199f * y;
        ym[n][2] = 0.4886025119029199f * z;
        ym[n][3] = 0.4886025119029199f * x;
        ym[n][4] = 1.0925484305920792f * x * y;
        ym[n][5] = 1.0925484305920792f * y * z;
        ym[n][6] = 0.31539156525252005f * (3.0f * z * z - 1.0f);
        ym[n][7] = 1.0925484305920792f * x * z;
        ym[n][8] = 0.5462742152960396f * (x * x - y * y);
        // ballot compaction (wave 0 only; t==lane)
        unsigned long long mask = __ballot(m);
        int rank = __popcll(mask & ((1ull << n) - 1ull));
        if (m) alist[rank] = n;
        if (n == 0) cnt_s = (int)__popcll(mask);
    }
    __syncthreads();
    int cnt = cnt_s;
    // compact ym rows
    for (int i = t; i < cnt * 9; i += 256) {
        int ci = i / 9, yi = i - ci * 9;
        ymc[ci][yi] = ym[alist[ci]][yi];
    }
    // compacted float4 gather+lerp: 18 float4 groups per active neighbor
    for (int i = t; i < cnt * 18; i += 256) {
        int ci = i / 18, q = i - ci * 18;
        int n = alist[ci];
        const float* g = &G[(size_t)t0s[n] * GC + zs[n] * LOD + 4 * q];
        float4 g0 = *(const float4*)g;
        float4 g1 = *(const float4*)(g + GC);
        float wl = wls[n];
        float4 v;
        v.x = g0.x + wl * (g1.x - g0.x);
        v.y = g0.y + wl * (g1.y - g0.y);
        v.z = g0.z + wl * (g1.z - g0.z);
        v.w = g0.w + wl * (g1.w - g0.w);
        *(float4*)&ps[ci][4 * q] = v;
    }
    __syncthreads();
    if (t < 216) {
        int lo, yi;
        if (t < 24) { lo = t; yi = 0; }
        else if (t < 96) { int q = t - 24; int o = q / 3; lo = 24 + o; yi = 1 + (q - o * 3); }
        else { int q = t - 96; int o = q / 5; lo = 48 + o; yi = 4 + (q - o * 5); }
        float acc = 0.0f;
        #pragma unroll 4
        for (int ci = 0; ci < cnt; ++ci)
            acc = fmaf(ps[ci][lo], ymc[ci][yi], acc);
        xr[3 + t] = acc * 0.125f;
    } else if (t < 219) {
        xr[t - 216] = body23[(size_t)ba * 3 + (t - 216)];
    }
    __syncthreads();
    if (t < CR) {
        float xv = xr[t];
        feats0[(size_t)ba * CR + t] = xv;
        atomicAdd(&pooled2[b * C2 + t], xv * xv);
    }
}

// residual GEMM: 2 same-b atoms/block, 512 blocks (2/CU), unroll 8 for load ILP.
// o = xv + sp5(res_b + xr.res_W); accumulate o^2 into pooled2 half 2.
__global__ void __launch_bounds__(256) k_redB(const float* __restrict__ feats0,
                                              const float* __restrict__ res_W,
                                              const float* __restrict__ res_b,
                                              float* __restrict__ pooled2) {
    int bp = blockIdx.x;                     // 512 blocks: b = bp>>5, atoms 2*(bp&31)..+1
    int b = bp >> 5;
    int a0 = (bp & 31) * 2;
    int t = threadIdx.x;
    __shared__ float xs[2][224];
    for (int i = t; i < 2 * CR; i += 256) {
        int r = i / CR, c = i - r * CR;
        xs[r][c] = feats0[(size_t)(b * cN + a0 + r) * CR + c];
    }
    __syncthreads();
    if (t < CR) {
        float s0 = 0.0f, s1 = 0.0f;
        #pragma unroll 8
        for (int k = 0; k < CR; ++k) {
            float w = res_W[(size_t)k * CR + t];
            s0 = fmaf(xs[0][k], w, s0);
            s1 = fmaf(xs[1][k], w, s1);
        }
        float rb = res_b[t];
        float o0 = xs[0][t] + sp5(rb + s0);
        float o1 = xs[1][t] + sp5(rb + s1);
        atomicAdd(&pooled2[b * C2 + CR + t], o0 * o0 + o1 * o1);
    }
}

// hh[b][j] = sp1(sqrt(pooled2[b]) . c_Wt[j] + c_b[j]); one block per column j, 64 lanes
__global__ void __launch_bounds__(64) k_head1(const float* __restrict__ pooled2,
                                              const float* __restrict__ c_Wt,
                                              const float* __restrict__ c_b,
                                              float* __restrict__ hh) {
    int j = blockIdx.x;
    int l = threadIdx.x;
    float acc[cB];
    #pragma unroll
    for (int b = 0; b < cB; ++b) acc[b] = 0.0f;
    const float* wr = &c_Wt[j * 440];
    for (int ch = l; ch < C2; ch += 64) {
        float wv = wr[ch];
        #pragma unroll
        for (int b = 0; b < cB; ++b)
            acc[b] = fmaf(sqrtf(pooled2[b * C2 + ch]), wv, acc[b]);
    }
    #pragma unroll
    for (int off = 32; off >= 1; off >>= 1) {
        #pragma unroll
        for (int b = 0; b < cB; ++b) acc[b] += __shfl_xor(acc[b], off, 64);
    }
    if (l == 0) {
        float cb = c_b[j];
        #pragma unroll
        for (int b = 0; b < cB; ++b) hh[b * HD + j] = sp1(acc[b] + cb);
    }
}

// BN (training batch stats) + softplus + output linear + sigmoid; single small block
__global__ void __launch_bounds__(128) k_head2(const float* __restrict__ hh,
                                               const float* __restrict__ bn_g,
                                               const float* __restrict__ bn_b,
                                               const float* __restrict__ o_W,
                                               const float* __restrict__ o_b,
                                               float* __restrict__ out) {
    __shared__ float hh2[cB][HD];
    int t = threadIdx.x;                     // = column j
    float v[cB];
    float mu = 0.0f;
    #pragma unroll
    for (int b = 0; b < cB; ++b) { v[b] = hh[b * HD + t]; mu += v[b]; }
    mu *= (1.0f / cB);
    float var = 0.0f;
    #pragma unroll
    for (int b = 0; b < cB; ++b) { float d = v[b] - mu; var = fmaf(d, d, var); }
    var *= (1.0f / cB);
    float sc = bn_g[t] / sqrtf(var + 1e-5f);
    float bnb = bn_b[t];
    #pragma unroll
    for (int b = 0; b < cB; ++b) hh2[b][t] = sp1((v[b] - mu) * sc + bnb);
    __syncthreads();
    if (t < cB) {
        float s = o_b[0];
        for (int j = 0; j < HD; ++j) s = fmaf(hh2[t][j], o_W[j], s);
        out[t] = 1.0f / (1.0f + expf(-s));
    }
}

extern "C" void kernel_launch(void* const* d_in, const int* in_sizes, int n_in,
                              void* d_out, int out_size, void* d_ws, size_t ws_size,
                              hipStream_t stream) {
    const float* xyz    = (const float*)d_in[0];
    const int*   Z      = (const int*)d_in[1];
    const float* body23 = (const float*)d_in[2];
    const float* emb_W  = (const float*)d_in[3];
    const float* rW0    = (const float*)d_in[4];
    const float* rb0    = (const float*)d_in[5];
    const float* rW1    = (const float*)d_in[6];
    const float* rb1    = (const float*)d_in[7];
    const float* rW2    = (const float*)d_in[8];
    const float* rb2    = (const float*)d_in[9];
    const float* rW3    = (const float*)d_in[10];
    const float* rb3    = (const float*)d_in[11];
    const float* res_W  = (const float*)d_in[12];
    const float* res_b  = (const float*)d_in[13];
    const float* c_W    = (const float*)d_in[14];
    const float* c_b    = (const float*)d_in[15];
    const float* bn_g   = (const float*)d_in[16];
    const float* bn_b   = (const float*)d_in[17];
    const float* o_W    = (const float*)d_in[18];
    const float* o_b    = (const float*)d_in[19];

    float* w       = (float*)d_ws;
    float* W2      = w;                       // 150*512    = 76800
    float* Pbz     = W2 + 76800;              // 432
    float* rW0p    = Pbz + 432;               // 10*152     = 1520
    float* rW1p    = rW0p + 1520;             // 150*152    = 22800
    float* rW2p    = rW1p + 22800;            // 22800
    float* c_Wt    = rW2p + 22800;            // 128*440    = 56320
    float* G       = c_Wt + 56320;            // 512*432    = 221184
    float* feats0  = G + 221184;              // 1024*219   = 224256
    float* pooled2 = feats0 + 224256;         // 16*438     = 7008
    float* hh      = pooled2 + 7008;          // 16*128     = 2048
    float* touch   = hh + 2048;               // 64*256     = 16384
    (void)in_sizes; (void)n_in; (void)out_size; (void)ws_size;

    k_prep <<<410, 256, 0, stream>>>(emb_W, rW3, rb3, rW0, rW1, rW2, c_W, res_W,
                                     W2, Pbz, rW0p, rW1p, rW2p, c_Wt, pooled2, touch);
    k_chain<<<TBL / 2, 256, 0, stream>>>(rW0p, rb0, rW1p, rb1, rW2p, rb2, W2, Pbz, G);
    k_redA <<<cB * cN, 256, 0, stream>>>(xyz, Z, body23, G, feats0, pooled2);
    k_redB <<<cB * cN / 2, 256, 0, stream>>>(feats0, res_W, res_b, pooled2);
    k_head1<<<HD, 64, 0, stream>>>(pooled2, c_Wt, c_b, hh);
    k_head2<<<1, 128, 0, stream>>>(hh, bn_g, bn_b, o_W, o_b, (float*)d_out);
}

// Round 25
// 66.660 us; speedup vs baseline: 1.1548x; 1.0151x over previous
//
#include <hip/hip_runtime.h>
#include <math.h>

constexpr int cB  = 16;
constexpr int cN  = 64;
constexpr int EMB = 32;
constexpr int NL  = 3;
constexpr int CDIM = 24;
constexpr int LOD = NL * CDIM;      // 72
constexpr int NB  = 10;
constexpr int H   = 150;
constexpr int CR  = 219;
constexpr int C2  = 438;
constexpr int HD  = 128;
constexpr int NSP = 6;              // species count
constexpr int GC  = NSP * LOD;      // 432 G-columns
constexpr int GCP = 512;            // padded W2 row
constexpr int TBL = 512;            // r-table resolution (measured absmax 0.0)
constexpr float RADIUS = 2.0f;

__device__ __forceinline__ float sp5(float x) {
    return fmaxf(x, 0.0f) + 0.2f * log1pf(expf(-5.0f * fabsf(x)));
}
__device__ __forceinline__ float sp1(float x) {
    return fmaxf(x, 0.0f) + log1pf(expf(-fabsf(x)));
}

// Merged prologue kernel.
// blocks 0..89: W2 build + Pbz; blocks 90..345: pad/transpose + zero pooled2;
// blocks 346..409: warm-touch res_W into L2/L3 (cold-replay latency hiding).
__global__ void __launch_bounds__(256) k_prep(const float* __restrict__ emb_W,
                                              const float* __restrict__ rW3,
                                              const float* __restrict__ rb3,
                                              const float* __restrict__ rW0,
                                              const float* __restrict__ rW1,
                                              const float* __restrict__ rW2,
                                              const float* __restrict__ c_W,
                                              const float* __restrict__ res_W,
                                              float* __restrict__ W2,
                                              float* __restrict__ Pbz,
                                              float* __restrict__ rW0p,
                                              float* __restrict__ rW1p,
                                              float* __restrict__ rW2p,
                                              float* __restrict__ c_Wt,
                                              float* __restrict__ pooled2,
                                              float* __restrict__ touch) {
    int bx = blockIdx.x;
    int t = threadIdx.x;
    __shared__ float e[EMB];
    if (bx < 90) {
        int z = bx / 15, hb = bx - (bx / 15) * 15;   // 6 x 15, 10 k-rows each
        if (t < EMB) e[t] = emb_W[z * EMB + t];
        __syncthreads();
        for (int o = t; o < 10 * LOD; o += 256) {
            int k = hb * 10 + o / LOD, lo = o % LOD;
            const float* wr = &rW3[(size_t)k * (LOD * EMB) + lo * EMB];
            float s = 0.0f;
            #pragma unroll
            for (int i = 0; i < EMB; ++i) s = fmaf(wr[i], e[i], s);
            W2[(size_t)k * GCP + z * LOD + lo] = s;
        }
        if (z == 0) {  // zero the pad cols 432..511
            for (int o = t; o < 10 * (GCP - GC); o += 256) {
                int k = hb * 10 + o / (GCP - GC), c = GC + o % (GCP - GC);
                W2[(size_t)k * GCP + c] = 0.0f;
            }
        }
        if (hb == 0 && t < LOD) {
            float s = 0.0f;
            #pragma unroll
            for (int i = 0; i < EMB; ++i) s = fmaf(rb3[t * EMB + i], e[i], s);
            Pbz[z * LOD + t] = s;
        }
    } else if (bx < 346) {
        int pb = bx - 90;                            // 256 pad blocks
        int total = NB * 152 + 2 * H * 152 + HD * 440;   // 103440
        int total2 = total + cB * C2;                    // + pooled2 zeroing
        for (int i = pb * 256 + t; i < total2; i += 256 * 256) {
            if (i < NB * 152) {
                int r = i / 152, c = i - r * 152;
                rW0p[i] = (c < H) ? rW0[r * H + c] : 0.0f;
            } else if (i < NB * 152 + H * 152) {
                int j = i - NB * 152; int r = j / 152, c = j - r * 152;
                rW1p[j] = (c < H) ? rW1[r * H + c] : 0.0f;
            } else if (i < NB * 152 + 2 * H * 152) {
                int j = i - NB * 152 - H * 152; int r = j / 152, c = j - r * 152;
                rW2p[j] = (c < H) ? rW2[r * H + c] : 0.0f;
            } else if (i < total) {
                int j = i - NB * 152 - 2 * H * 152;
                int jj = j / 440, ch = j - jj * 440;
                c_Wt[j] = (ch < C2) ? c_W[ch * HD + jj] : 0.0f;
            } else {
                pooled2[i - total] = 0.0f;
            }
        }
    } else {
        // warm-touch res_W: 64 blocks x 256 thr, float4-coalesced; live dummy write
        int wb = bx - 346;
        const int n4 = (CR * CR) / 4;                // 11990 float4s
        float s = 0.0f;
        for (int i = wb * 256 + t; i < n4; i += 64 * 256) {
            float4 v = *(const float4*)&res_W[4 * i];
            s += v.x + v.y + v.z + v.w;
        }
        touch[wb * 256 + t] = s;                     // deterministic, keeps loads live
    }
}

// Fused table chain, no weight staging (weights stream L1/L2, coalesced).
// 2 rows/block x 256 thr; thread map: a2 = t>>7 (row), jt = t&127 (col).
__global__ void __launch_bounds__(256) k_chain(const float* __restrict__ rW0p,
                                               const float* __restrict__ rb0,
                                               const float* __restrict__ rW1p,
                                               const float* __restrict__ rb1,
                                               const float* __restrict__ rW2p,
                                               const float* __restrict__ rb2,
                                               const float* __restrict__ W2,
                                               const float* __restrict__ Pbz,
                                               float* __restrict__ G) {
    const int row0 = blockIdx.x * 2;
    const int t = threadIdx.x;
    const int a2 = t >> 7;                   // 0..1 local row
    const int jt = t & 127;                  // col
    const bool hasx = (jt < 22);
    const int jx = hasx ? 128 + jt : 128;    // extra col (idle lanes read col 128, discard)

    __shared__ __align__(16) float bas[2][10];
    __shared__ __align__(16) float hA[2 * 152];
    __shared__ __align__(16) float hB[2 * 152];

    if (t < 2) {
        float r = (float)(row0 + t) * (RADIUS / (float)(TBL - 1));
        #pragma unroll
        for (int k = 0; k < NB; ++k) {
            float d = r * 4.5f - (float)k;
            float v = 0.0f;
            if (fabsf(d) < 1.0f) { float cc = cosf(1.57079632679489662f * d); v = cc * cc; }
            bas[t][k] = v;
        }
    }
    __syncthreads();

    // ---- L0: K=10 ----
    {
        float a0 = 0, ax = 0;
        #pragma unroll
        for (int k = 0; k < NB; ++k) {
            float x = bas[a2][k];
            a0 = fmaf(x, rW0p[k * 152 + jt], a0);
            ax = fmaf(x, rW0p[k * 152 + jx], ax);
        }
        hA[a2 * 152 + jt] = sp5(a0 + rb0[jt]);
        if (hasx) hA[a2 * 152 + 128 + jt] = sp5(ax + rb0[128 + jt]);
    }
    __syncthreads();

    // ---- L1 (hA->hB), L2 (hB->hA): K=150, weights direct from L1/L2 ----
    for (int layer = 0; layer < 2; ++layer) {
        const float* W   = layer ? rW2p : rW1p;
        const float* bb  = layer ? rb2 : rb1;
        const float* src = layer ? hB : hA;
        float*       dst = layer ? hA : hB;
        float a0 = 0, ax = 0;
        const float* xs = &src[a2 * 152];
        #pragma unroll 10
        for (int k = 0; k < H; ++k) {
            float x = xs[k];
            const float* wr = &W[k * 152];
            a0 = fmaf(x, wr[jt], a0);
            ax = fmaf(x, wr[jx], ax);
        }
        dst[a2 * 152 + jt] = sp5(a0 + bb[jt]);
        if (hasx) dst[a2 * 152 + 128 + jt] = sp5(ax + bb[128 + jt]);
        __syncthreads();
    }

    // ---- G: out[row][c] = sum_k hA[row][k]*W2[k][c] + Pbz[c], c = 4jt..4jt+4 ----
    if (jt < 108) {
        const int g0 = 4 * jt;
        float4 c0 = {0, 0, 0, 0};
        const float* xs = &hA[a2 * 152];
        #pragma unroll 10
        for (int k = 0; k < H; ++k) {
            float x = xs[k];
            float4 w = *(const float4*)&W2[(size_t)k * GCP + g0];
            c0.x = fmaf(x, w.x, c0.x); c0.y = fmaf(x, w.y, c0.y);
            c0.z = fmaf(x, w.z, c0.z); c0.w = fmaf(x, w.w, c0.w);
        }
        int row = row0 + a2;
        float4 p = *(const float4*)&Pbz[g0];
        float4 o;
        o.x = c0.x + p.x; o.y = c0.y + p.y; o.z = c0.z + p.z; o.w = c0.w + p.w;
        *(float4*)&G[(size_t)row * GC + g0] = o;
    }
}

// Fully fused per (b,a): ballot-compacted gather + Y-reduce -> xr; in-block residual
// GEMM vs L2-warm res_W; xv^2 and o^2 atomically accumulated into pooled2.
__global__ void __launch_bounds__(256) k_red(const float* __restrict__ xyz,
                                             const int* __restrict__ Z,
                                             const float* __restrict__ body23,
                                             const float* __restrict__ G,
                                             const float* __restrict__ res_W,
                                             const float* __restrict__ res_b,
                                             float* __restrict__ pooled2) {
    int ba = blockIdx.x;
    int b = ba >> 6, a = ba & 63;
    int t = threadIdx.x;
    __shared__ float ym[64][12];
    __shared__ float ymc[64][12];
    __shared__ __align__(16) float ps[64][76];
    __shared__ float xr[224];
    __shared__ int t0s[64];
    __shared__ float wls[64];
    __shared__ int zs[64];
    __shared__ int alist[64];
    __shared__ int cnt_s;
    if (t < 64) {
        int n = t;
        float ax = xyz[((size_t)b * cN + a) * 3 + 0];
        float ay = xyz[((size_t)b * cN + a) * 3 + 1];
        float az = xyz[((size_t)b * cN + a) * 3 + 2];
        float d0 = ax - xyz[((size_t)b * cN + n) * 3 + 0];
        float d1 = ay - xyz[((size_t)b * cN + n) * 3 + 1];
        float d2 = az - xyz[((size_t)b * cN + n) * 3 + 2];
        float s = d0 * d0 + d1 * d1 + d2 * d2;
        float r = sqrtf(s + 1e-12f);
        bool m = (r < RADIUS) && (r > 1e-6f);
        float u = r * ((float)(TBL - 1) / RADIUS);
        int t0 = (int)u;
        if (t0 > TBL - 2) t0 = TBL - 2;
        t0s[n] = t0;
        wls[n] = u - (float)t0;
        zs[n] = Z[b * cN + n];
        float inv = 1.0f / r;
        float x = d0 * inv, y = d1 * inv, z = d2 * inv;
        ym[n][0] = 0.28209479177387814f;
        ym[n][1] = 0.4886025119029199f * y;
        ym[n][2] = 0.4886025119029199f * z;
        ym[n][3] = 0.4886025119029199f * x;
        ym[n][4] = 1.0925484305920792f * x * y;
        ym[n][5] = 1.0925484305920792f * y * z;
        ym[n][6] = 0.31539156525252005f * (3.0f * z * z - 1.0f);
        ym[n][7] = 1.0925484305920792f * x * z;
        ym[n][8] = 0.5462742152960396f * (x * x - y * y);
        // ballot compaction (wave 0 only; t==lane)
        unsigned long long mask = __ballot(m);
        int rank = __popcll(mask & ((1ull << n) - 1ull));
        if (m) alist[rank] = n;
        if (n == 0) cnt_s = (int)__popcll(mask);
    }
    __syncthreads();
    int cnt = cnt_s;
    // compact ym rows
    for (int i = t; i < cnt * 9; i += 256) {
        int ci = i / 9, yi = i - ci * 9;
        ymc[ci][yi] = ym[alist[ci]][yi];
    }
    // compacted float4 gather+lerp: 18 float4 groups per active neighbor
    for (int i = t; i < cnt * 18; i += 256) {
        int ci = i / 18, q = i - ci * 18;
        int n = alist[ci];
        const float* g = &G[(size_t)t0s[n] * GC + zs[n] * LOD + 4 * q];
        float4 g0 = *(const float4*)g;
        float4 g1 = *(const float4*)(g + GC);
        float wl = wls[n];
        float4 v;
        v.x = g0.x + wl * (g1.x - g0.x);
        v.y = g0.y + wl * (g1.y - g0.y);
        v.z = g0.z + wl * (g1.z - g0.z);
        v.w = g0.w + wl * (g1.w - g0.w);
        *(float4*)&ps[ci][4 * q] = v;
    }
    __syncthreads();
    if (t < 216) {
        int lo, yi;
        if (t < 24) { lo = t; yi = 0; }
        else if (t < 96) { int q = t - 24; int o = q / 3; lo = 24 + o; yi = 1 + (q - o * 3); }
        else { int q = t - 96; int o = q / 5; lo = 48 + o; yi = 4 + (q - o * 5); }
        float acc = 0.0f;
        #pragma unroll 4
        for (int ci = 0; ci < cnt; ++ci)
            acc = fmaf(ps[ci][lo], ymc[ci][yi], acc);
        xr[3 + t] = acc * 0.125f;
    } else if (t < 219) {
        xr[t - 216] = body23[(size_t)ba * 3 + (t - 216)];
    }
    __syncthreads();
    // in-block residual: s[t] = sum_k xr[k] * res_W[k][t]  (coalesced, L2-warm)
    if (t < CR) {
        float xv = xr[t];
        float s = 0.0f;
        #pragma unroll 8
        for (int k = 0; k < CR; ++k)
            s = fmaf(xr[k], res_W[(size_t)k * CR + t], s);
        float o = xv + sp5(res_b[t] + s);
        atomicAdd(&pooled2[b * C2 + t],      xv * xv);
        atomicAdd(&pooled2[b * C2 + CR + t], o * o);
    }
}

// hh[b][j] = sp1(sqrt(pooled2[b]) . c_Wt[j] + c_b[j]); one block per column j, 64 lanes
__global__ void __launch_bounds__(64) k_head1(const float* __restrict__ pooled2,
                                              const float* __restrict__ c_Wt,
                                              const float* __restrict__ c_b,
                                              float* __restrict__ hh) {
    int j = blockIdx.x;
    int l = threadIdx.x;
    float acc[cB];
    #pragma unroll
    for (int b = 0; b < cB; ++b) acc[b] = 0.0f;
    const float* wr = &c_Wt[j * 440];
    for (int ch = l; ch < C2; ch += 64) {
        float wv = wr[ch];
        #pragma unroll
        for (int b = 0; b < cB; ++b)
            acc[b] = fmaf(sqrtf(pooled2[b * C2 + ch]), wv, acc[b]);
    }
    #pragma unroll
    for (int off = 32; off >= 1; off >>= 1) {
        #pragma unroll
        for (int b = 0; b < cB; ++b) acc[b] += __shfl_xor(acc[b], off, 64);
    }
    if (l == 0) {
        float cb = c_b[j];
        #pragma unroll
        for (int b = 0; b < cB; ++b) hh[b * HD + j] = sp1(acc[b] + cb);
    }
}

// BN (training batch stats) + softplus + output linear + sigmoid; single small block
__global__ void __launch_bounds__(128) k_head2(const float* __restrict__ hh,
                                               const float* __restrict__ bn_g,
                                               const float* __restrict__ bn_b,
                                               const float* __restrict__ o_W,
                                               const float* __restrict__ o_b,
                                               float* __restrict__ out) {
    __shared__ float hh2[cB][HD];
    int t = threadIdx.x;                     // = column j
    float v[cB];
    float mu = 0.0f;
    #pragma unroll
    for (int b = 0; b < cB; ++b) { v[b] = hh[b * HD + t]; mu += v[b]; }
    mu *= (1.0f / cB);
    float var = 0.0f;
    #pragma unroll
    for (int b = 0; b < cB; ++b) { float d = v[b] - mu; var = fmaf(d, d, var); }
    var *= (1.0f / cB);
    float sc = bn_g[t] / sqrtf(var + 1e-5f);
    float bnb = bn_b[t];
    #pragma unroll
    for (int b = 0; b < cB; ++b) hh2[b][t] = sp1((v[b] - mu) * sc + bnb);
    __syncthreads();
    if (t < cB) {
        float s = o_b[0];
        for (int j = 0; j < HD; ++j) s = fmaf(hh2[t][j], o_W[j], s);
        out[t] = 1.0f / (1.0f + expf(-s));
    }
}

extern "C" void kernel_launch(void* const* d_in, const int* in_sizes, int n_in,
                              void* d_out, int out_size, void* d_ws, size_t ws_size,
                              hipStream_t stream) {
    const float* xyz    = (const float*)d_in[0];
    const int*   Z      = (const int*)d_in[1];
    const float* body23 = (const float*)d_in[2];
    const float* emb_W  = (const float*)d_in[3];
    const float* rW0    = (const float*)d_in[4];
    const float* rb0    = (const float*)d_in[5];
    const float* rW1    = (const float*)d_in[6];
    const float* rb1    = (const float*)d_in[7];
    const float* rW2    = (const float*)d_in[8];
    const float* rb2    = (const float*)d_in[9];
    const float* rW3    = (const float*)d_in[10];
    const float* rb3    = (const float*)d_in[11];
    const float* res_W  = (const float*)d_in[12];
    const float* res_b  = (const float*)d_in[13];
    const float* c_W    = (const float*)d_in[14];
    const float* c_b    = (const float*)d_in[15];
    const float* bn_g   = (const float*)d_in[16];
    const float* bn_b   = (const float*)d_in[17];
    const float* o_W    = (const float*)d_in[18];
    const float* o_b    = (const float*)d_in[19];

    float* w       = (float*)d_ws;
    float* W2      = w;                       // 150*512    = 76800
    float* Pbz     = W2 + 76800;              // 432
    float* rW0p    = Pbz + 432;               // 10*152     = 1520
    float* rW1p    = rW0p + 1520;             // 150*152    = 22800
    float* rW2p    = rW1p + 22800;            // 22800
    float* c_Wt    = rW2p + 22800;            // 128*440    = 56320
    float* G       = c_Wt + 56320;            // 512*432    = 221184
    float* pooled2 = G + 221184;              // 16*438     = 7008
    float* hh      = pooled2 + 7008;          // 16*128     = 2048
    float* touch   = hh + 2048;               // 64*256     = 16384
    (void)in_sizes; (void)n_in; (void)out_size; (void)ws_size;

    k_prep <<<410, 256, 0, stream>>>(emb_W, rW3, rb3, rW0, rW1, rW2, c_W, res_W,
                                     W2, Pbz, rW0p, rW1p, rW2p, c_Wt, pooled2, touch);
    k_chain<<<TBL / 2, 256, 0, stream>>>(rW0p, rb0, rW1p, rb1, rW2p, rb2, W2, Pbz, G);
    k_red  <<<cB * cN, 256, 0, stream>>>(xyz, Z, body23, G, res_W, res_b, pooled2);
    k_head1<<<HD, 64, 0, stream>>>(pooled2, c_Wt, c_b, hh);
    k_head2<<<1, 128, 0, stream>>>(hh, bn_g, bn_b, o_W, o_b, (float*)d_out);
}